// Round 9
// baseline (268.745 us; speedup 1.0000x reference)
//
#include <hip/hip_runtime.h>

// MiniGPT fused forward. Inputs fp32 (x int32/int64 auto), OUTPUT fp32 (proven r5).
// R9: intra-block split-K attention. 256 thr = (2 q-subwaves) x (2 k-phases); phase p
// owns tiles p,p+2,... in its own K/V LDS buffers (72KB, 2 blocks/CU -> 2 waves/SIMD,
// 2x TLP, half the serial tile chain). Per-phase compute core = r7-verified swapped-QK
// (stage->barrier->compute, un-sinkable). Final online-softmax combine in LDS.
// r8 lesson: reg-staged prefetch gets re-sunk by hipcc (VGPR 164->132, 2 exposed
// latencies/tile) -- LDS staging with barriers is the deterministic structure.
// qkv (768 blocks, W direct), tok_prep, wconv kept from r8.

#define TWIN 2048
#define NEMB 256
#define NB   8
#define VOCAB 50257
#define NTOK (NB * TWIN)

typedef __attribute__((ext_vector_type(8))) short s16x8;
typedef __attribute__((ext_vector_type(4))) float f32x4;
typedef __attribute__((ext_vector_type(4))) float f4;
typedef unsigned short u16;
typedef unsigned int   u32;

__device__ __forceinline__ u16 f2bf(float f) {
    union { float f; u32 i; } x; x.f = f;
    u32 r = x.i + 0x7fffu + ((x.i >> 16) & 1u);
    return (u16)(r >> 16);
}
__device__ __forceinline__ u32 pack2bf(float a, float b) {
    return (u32)f2bf(a) | ((u32)f2bf(b) << 16);
}

// ---------------- W fp32 -> bf16, once ----------------
__global__ __launch_bounds__(256) void wconv_kernel(
    const float* __restrict__ Wq, const float* __restrict__ Wk,
    const float* __restrict__ Wv, u16* __restrict__ Wb)
{
    int b = blockIdx.x;
    int which = b >> 5;
    int off = (b & 31) * 2048 + threadIdx.x * 8;
    const float* src = (which == 0) ? Wq : ((which == 1) ? Wk : Wv);
    f4 v0 = *(const f4*)(src + off);
    f4 v1 = *(const f4*)(src + off + 4);
    u16 ww[8];
#pragma unroll
    for (int i = 0; i < 4; i++) { ww[i] = f2bf(v0[i]); ww[4 + i] = f2bf(v1[i]); }
    *(uint4*)(Wb + which * 65536 + off) = *(uint4*)ww;
}

// ---------------- token index prep (parallel; int32/int64 vote) ----------------
__global__ __launch_bounds__(256) void tok_prep(const void* xraw, int* tokidx) {
    const long long* x64 = (const long long*)xraw;
    const int*       x32 = (const int*)xraw;
    long long probe = x64[threadIdx.x & 63];
    int ok = (probe >= 0 && probe < VOCAB) ? 1 : 0;
    int is64 = __all(ok);
    int i = blockIdx.x * 256 + threadIdx.x;
    int v = is64 ? (int)x64[i] : x32[i];
    tokidx[i] = (v < 0) ? 0 : ((v >= VOCAB) ? (VOCAB - 1) : v);
}

// ---------------- Kernel A: h build + one-matrix projection per block ----------------
__global__ __launch_bounds__(256) void qkv_kernel(
    const int* __restrict__ tokidx,
    const float* __restrict__ tok, const float* __restrict__ pos,
    const u16* __restrict__ Wb,
    const float* __restrict__ bqp, const float* __restrict__ bkp,
    const float* __restrict__ bvp,
    u16* __restrict__ Qg, u16* __restrict__ Kg, u16* __restrict__ Vt)
{
    __shared__ u16 h_lds[64 * 256];

    const int tid   = threadIdx.x;
    const int which = blockIdx.x >> 8;               // 0=Q 1=K 2=V
    const int t0    = (blockIdx.x & 255) * 64;
    const int bb    = t0 >> 11;
    const int tl0   = t0 & (TWIN - 1);

#pragma unroll
    for (int j = 0; j < 8; j++) {
        int c   = tid + 256 * j;
        int row = c >> 5, col = c & 31;
        int t   = t0 + row;
        int xi  = tokidx[t];
        const float* tp = tok + (size_t)xi * NEMB + col * 8;
        const float* pp = pos + (size_t)(t & (TWIN - 1)) * NEMB + col * 8;
        f4 a0 = *(const f4*)tp, a1 = *(const f4*)(tp + 4);
        f4 b0 = *(const f4*)pp, b1 = *(const f4*)(pp + 4);
        u16 hh[8];
#pragma unroll
        for (int i = 0; i < 4; i++) {
            hh[i]     = f2bf(a0[i] + b0[i]);
            hh[4 + i] = f2bf(a1[i] + b1[i]);
        }
        *(uint4*)((char*)h_lds + row * 512 + ((col * 16) ^ ((row & 7) << 4))) = *(uint4*)hh;
    }
    __syncthreads();

    const int wid = tid >> 6, lane = tid & 63, g = lane >> 4, lr = lane & 15;
    const u16* Wp = Wb + which * 65536;
    const float* Bp = (which == 0) ? bqp : ((which == 1) ? bkp : bvp);

    f32x4 acc[16];
#pragma unroll
    for (int i = 0; i < 16; i++) acc[i] = (f32x4){0.f, 0.f, 0.f, 0.f};

#pragma unroll
    for (int es = 0; es < 8; es++) {
        int arow = wid * 16 + lr;
        s16x8 af = *(const s16x8*)((const char*)h_lds + arow * 512 +
                                   ((es * 64 + g * 16) ^ ((arow & 7) << 4)));
        s16x8 bfv[16];
#pragma unroll
        for (int ct = 0; ct < 16; ct++)
            bfv[ct] = *(const s16x8*)(Wp + (size_t)(ct * 16 + lr) * NEMB + es * 32 + g * 8);
#pragma unroll
        for (int ct = 0; ct < 16; ct++)
            acc[ct] = __builtin_amdgcn_mfma_f32_16x16x32_bf16(af, bfv[ct], acc[ct], 0, 0, 0);
    }

    if (which < 2) {
        u16* dst = (which == 0) ? Qg : Kg;
        __syncthreads();
#pragma unroll
        for (int ct = 0; ct < 16; ct++) {
            float bias = Bp[ct * 16 + lr];
#pragma unroll
            for (int r = 0; r < 4; r++)
                h_lds[(wid * 16 + 4 * g + r) * 256 + ct * 16 + lr] = f2bf(acc[ct][r] + bias);
        }
        __syncthreads();
#pragma unroll
        for (int j = 0; j < 8; j++) {
            int c = tid + 256 * j;
            int row = c >> 5, col = c & 31;
            uint4 v = *(const uint4*)(h_lds + row * 256 + col * 8);
            *(uint4*)(dst + (size_t)(t0 + row) * NEMB + col * 8) = v;
        }
    } else {
#pragma unroll
        for (int ct = 0; ct < 16; ct++) {
            float bias = Bp[ct * 16 + lr];
            u16 pk[4];
#pragma unroll
            for (int r = 0; r < 4; r++) pk[r] = f2bf(acc[ct][r] + bias);
            int e = ct * 16 + lr;
            *(ushort4*)(Vt + ((size_t)bb * NEMB + e) * TWIN + tl0 + wid * 16 + 4 * g)
                = *(ushort4*)pk;
        }
    }
}

// ---------------- Kernel B: causal flash attention, intra-block split-K ----------------
// 512 blocks x 256 thr. wid = tid>>6: qsub = wid&1 (16 q-rows each), ph = wid>>1
// (k-phase: tiles ph, ph+2, ...). Per-phase K/V LDS buffers; online-softmax combine.
__global__ __launch_bounds__(256) void attn_kernel(
    const u16* __restrict__ Qg, const u16* __restrict__ Kg,
    const u16* __restrict__ Vt, float* __restrict__ outp)
{
    __shared__ char smem[73728];   // [K ph0 16KB][K ph1 16KB][V ph0 20KB][V ph1 20KB]

    const int tid = threadIdx.x;
    const int bid = blockIdx.x;
    const int bb  = bid & 7;
    const int idx = bid >> 3;
    const int qtile = (idx < 32) ? (63 - idx) : (idx - 32);   // pair-balanced
    const int q0 = qtile * 32;
    const int nt = qtile + 1;

    const u16* Qb = Qg + (size_t)bb * TWIN * NEMB;
    const u16* Kb = Kg + (size_t)bb * TWIN * NEMB;
    const u16* Vb = Vt + (size_t)bb * NEMB * TWIN;
    float* Ob = outp + (size_t)bb * TWIN * NEMB;

    const int lane = tid & 63;
    const int qsub = (tid >> 6) & 1;
    const int ph   = tid >> 7;                  // k-phase
    const int ptid = tid & 127;                 // thread id within phase
    const int q    = lane & 15, hi = lane >> 4;
    const int qrow = q0 + qsub * 16 + q;

    char* kbase = smem + ph * 16384;
    char* vbase = smem + 32768 + ph * 20480;

    s16x8 qf[8];
#pragma unroll
    for (int es = 0; es < 8; es++)
        qf[es] = *(const s16x8*)(Qb + (size_t)qrow * NEMB + es * 32 + hi * 8);

    f32x4 o[16];
#pragma unroll
    for (int i = 0; i < 16; i++) o[i] = (f32x4){0.f, 0.f, 0.f, 0.f};
    float m = -1.0e4f, l = 0.f;

    const int itmax = (nt + 1) >> 1;
    for (int it = 0; it < itmax; it++) {
        const int tt = 2 * it + ph;
        const bool active = (tt < nt);
        const int kb = tt * 32;

        __syncthreads();                        // prior compute's LDS reads done
        if (active) {
            // K tile [32][256]: linear dest, pre-swizzled source
#pragma unroll
            for (int j = 0; j < 8; j++) {
                int c = ptid + 128 * j;
                int row = c >> 5;
                int colb = ((c & 31) * 16) ^ ((row & 7) << 4);
                uint4 v = *(const uint4*)((const char*)(Kb + (size_t)(kb + row) * NEMB) + colb);
                *(uint4*)(kbase + c * 16) = v;
            }
            // V tile [256 e][32 k] -> 80B rows
#pragma unroll
            for (int j = 0; j < 8; j++) {
                int c = ptid + 128 * j;
                int e = c >> 2, hv = c & 3;
                uint4 v = *(const uint4*)(Vb + (size_t)e * TWIN + kb + hv * 8);
                *(uint4*)(vbase + e * 80 + hv * 16) = v;
            }
        }
        __syncthreads();
        if (!active) continue;

        // S^T = K·Q^T
        f32x4 st0 = (f32x4){0.f, 0.f, 0.f, 0.f};
        f32x4 st1 = (f32x4){0.f, 0.f, 0.f, 0.f};
#pragma unroll
        for (int es = 0; es < 8; es++) {
            s16x8 kf0 = *(const s16x8*)(kbase + q * 512 +
                                        ((es * 64 + hi * 16) ^ ((q & 7) << 4)));
            st0 = __builtin_amdgcn_mfma_f32_16x16x32_bf16(kf0, qf[es], st0, 0, 0, 0);
            int row1 = q + 16;
            s16x8 kf1 = *(const s16x8*)(kbase + row1 * 512 +
                                        ((es * 64 + hi * 16) ^ ((row1 & 7) << 4)));
            st1 = __builtin_amdgcn_mfma_f32_16x16x32_bf16(kf1, qf[es], st1, 0, 0, 0);
        }

        // causal mask (diagonal = globally last tile; belongs to one phase)
        if (tt == nt - 1) {
#pragma unroll
            for (int r = 0; r < 4; r++) {
                if (kb + 4 * hi + r > qrow)      st0[r] = -1.0e4f;
                if (kb + 16 + 4 * hi + r > qrow) st1[r] = -1.0e4f;
            }
        }

        // in-register softmax (2 shfl cross-hi)
        float tm = fmaxf(fmaxf(fmaxf(st0[0], st0[1]), fmaxf(st0[2], st0[3])),
                         fmaxf(fmaxf(st1[0], st1[1]), fmaxf(st1[2], st1[3])));
        tm = fmaxf(tm, __shfl_xor(tm, 16));
        tm = fmaxf(tm, __shfl_xor(tm, 32));
        if (__any(tm > m)) {
            float mn = fmaxf(m, tm);
            float sc = __expf(m - mn);
            m = mn; l *= sc;
            float scr[4];
#pragma unroll
            for (int r = 0; r < 4; r++) scr[r] = __shfl(sc, hi * 20 + r);
#pragma unroll
            for (int et = 0; et < 16; et++)
#pragma unroll
                for (int r = 0; r < 4; r++) o[et][r] *= scr[r];
        }
        float p0[4], p1[4];
#pragma unroll
        for (int r = 0; r < 4; r++) {
            p0[r] = __expf(st0[r] - m);
            p1[r] = __expf(st1[r] - m);
        }
        float rs = (p0[0] + p0[1]) + (p0[2] + p0[3]) + (p1[0] + p1[1]) + (p1[2] + p1[3]);
        rs += __shfl_xor(rs, 16);
        rs += __shfl_xor(rs, 32);
        l += rs;

        // P -> A-frag relayout in-register (8 shfl + select)
        u32 pk00 = pack2bf(p0[0], p0[1]), pk01 = pack2bf(p0[2], p0[3]);
        u32 pk10 = pack2bf(p1[0], p1[1]), pk11 = pack2bf(p1[2], p1[3]);
        int sA = (lane & 15) | ((lane & 16) << 1);
        int sB = sA + 16;
        u32 b00 = (u32)__shfl((int)pk00, sA), b01 = (u32)__shfl((int)pk01, sA);
        u32 b02 = (u32)__shfl((int)pk00, sB), b03 = (u32)__shfl((int)pk01, sB);
        u32 b10 = (u32)__shfl((int)pk10, sA), b11 = (u32)__shfl((int)pk11, sA);
        u32 b12 = (u32)__shfl((int)pk10, sB), b13 = (u32)__shfl((int)pk11, sB);
        bool c1 = (hi & 2) != 0;
        union { uint4 u; s16x8 v; } pu;
        pu.u.x = c1 ? b10 : b00;
        pu.u.y = c1 ? b11 : b01;
        pu.u.z = c1 ? b12 : b02;
        pu.u.w = c1 ? b13 : b03;
        s16x8 pf = pu.v;

        // O += P V from this phase's V buffer
#pragma unroll
        for (int et = 0; et < 16; et++) {
            s16x8 vf = *(const s16x8*)(vbase + (q + 16 * et) * 80 + hi * 16);
            o[et] = __builtin_amdgcn_mfma_f32_16x16x32_bf16(pf, vf, o[et], 0, 0, 0);
        }
    }

    // ---- combine phase partials (online-softmax merge), reusing smem ----
    float* o_sh = (float*)smem;                  // [2 qsub][16 row][260]
    float* m_sh = (float*)(smem + 33280);        // [2][16]
    float* l_sh = m_sh + 32;
    __syncthreads();                             // all compute/staging done
    if (ph == 1) {
        if (hi == 0) { m_sh[qsub * 16 + q] = m; l_sh[qsub * 16 + q] = l; }
#pragma unroll
        for (int et = 0; et < 16; et++)
#pragma unroll
            for (int r = 0; r < 4; r++)
                o_sh[(qsub * 16 + 4 * hi + r) * 260 + q + 16 * et] = o[et][r];
    }
    __syncthreads();
    if (ph == 0) {
        float mb = m_sh[qsub * 16 + q], lb = l_sh[qsub * 16 + q];
        float M  = fmaxf(m, mb);
        float fa = __expf(m - M), fb = __expf(mb - M);
        float L  = l * fa + lb * fb;
        float inv = 1.0f / L;
        fa *= inv; fb *= inv;
        float far[4], fbr[4];
#pragma unroll
        for (int r = 0; r < 4; r++) {
            far[r] = __shfl(fa, hi * 20 + r);
            fbr[r] = __shfl(fb, hi * 20 + r);
        }
#pragma unroll
        for (int et = 0; et < 16; et++) {
#pragma unroll
            for (int r = 0; r < 4; r++) {
                float ob = o_sh[(qsub * 16 + 4 * hi + r) * 260 + q + 16 * et];
                Ob[(size_t)(q0 + qsub * 16 + 4 * hi + r) * NEMB + q + 16 * et]
                    = o[et][r] * far[r] + ob * fbr[r];
            }
        }
    }
}

// ---------------- ws-too-small diagnostic ----------------
__global__ __launch_bounds__(256) void ws_diag(float* outp, int n, float val) {
    int i = blockIdx.x * 256 + threadIdx.x;
    if (i < n) outp[i] = (i == 0) ? val : 0.0f;
}

extern "C" void kernel_launch(void* const* d_in, const int* in_sizes, int n_in,
                              void* d_out, int out_size, void* d_ws, size_t ws_size,
                              hipStream_t stream)
{
    const void*  x   = d_in[0];
    const float* tok = (const float*)d_in[1];
    const float* pos = (const float*)d_in[2];
    const float* Wq  = (const float*)d_in[3];
    const float* bq  = (const float*)d_in[4];
    const float* Wk  = (const float*)d_in[5];
    const float* bk  = (const float*)d_in[6];
    const float* Wv  = (const float*)d_in[7];
    const float* bv  = (const float*)d_in[8];

    const size_t kvElems = (size_t)NB * TWIN * NEMB;
    const size_t need = 3 * kvElems * 2 + 3 * 65536 * 2 + NTOK * 4 + 64;

    if (ws_size < need) {
        float val = 1000.0f + (float)(ws_size >> 20);
        hipLaunchKernelGGL(ws_diag, dim3((out_size + 255) / 256), dim3(256), 0, stream,
                           (float*)d_out, out_size, val);
        return;
    }

    u16* Qg = (u16*)d_ws;
    u16* Kg = Qg + kvElems;
    u16* Vt = Kg + kvElems;
    u16* Wb = Vt + kvElems;
    int* tokidx = (int*)(Wb + 3 * 65536);

    hipLaunchKernelGGL(wconv_kernel, dim3(96), dim3(256), 0, stream, Wq, Wk, Wv, Wb);
    hipLaunchKernelGGL(tok_prep, dim3(64), dim3(256), 0, stream, x, tokidx);
    hipLaunchKernelGGL(qkv_kernel, dim3(768), dim3(256), 0, stream,
                       tokidx, tok, pos, Wb, bq, bk, bv, Qg, Kg, Vt);
    hipLaunchKernelGGL(attn_kernel, dim3(512), dim3(256), 0, stream,
                       Qg, Kg, Vt, (float*)d_out);
}

// Round 10
// 210.710 us; speedup vs baseline: 1.2754x; 1.2754x over previous
//
#include <hip/hip_runtime.h>

// MiniGPT fused forward. Inputs fp32 (x int32/int64 auto), OUTPUT fp32 (proven r5).
// R10: attn = r7 core + async global_load_lds double-buffer prefetch (T3 minimal
// 2-phase). DMA has no register consumer -> compiler cannot sink it (r8 lesson);
// barrier+vmcnt(0) per tile is the only drain. V re-laid in LDS as [4 kchunk][256 e]
// (16B rows, conflict-free reads, linear DMA dest + permuted global source).
// r9 lesson: split-K/4-wave lockstep adds latency per interval, no TLP on critical
// path. qkv (768 blocks, W direct), tok_prep, wconv unchanged (r8-verified).
// ws: Q | K | Vt (bf16, 8MB each) | Wb (384KB) | tokidx (~24.6MB, guarded).

#define TWIN 2048
#define NEMB 256
#define NB   8
#define VOCAB 50257
#define NTOK (NB * TWIN)

typedef __attribute__((ext_vector_type(8))) short s16x8;
typedef __attribute__((ext_vector_type(4))) float f32x4;
typedef __attribute__((ext_vector_type(4))) float f4;
typedef unsigned short u16;
typedef unsigned int   u32;

__device__ __forceinline__ u16 f2bf(float f) {
    union { float f; u32 i; } x; x.f = f;
    u32 r = x.i + 0x7fffu + ((x.i >> 16) & 1u);
    return (u16)(r >> 16);
}
__device__ __forceinline__ u32 pack2bf(float a, float b) {
    return (u32)f2bf(a) | ((u32)f2bf(b) << 16);
}
__device__ __forceinline__ void gload_lds16(const void* g, void* l) {
    __builtin_amdgcn_global_load_lds(
        (const __attribute__((address_space(1))) void*)g,
        (__attribute__((address_space(3))) void*)l, 16, 0, 0);
}

// ---------------- W fp32 -> bf16, once ----------------
__global__ __launch_bounds__(256) void wconv_kernel(
    const float* __restrict__ Wq, const float* __restrict__ Wk,
    const float* __restrict__ Wv, u16* __restrict__ Wb)
{
    int b = blockIdx.x;
    int which = b >> 5;
    int off = (b & 31) * 2048 + threadIdx.x * 8;
    const float* src = (which == 0) ? Wq : ((which == 1) ? Wk : Wv);
    f4 v0 = *(const f4*)(src + off);
    f4 v1 = *(const f4*)(src + off + 4);
    u16 ww[8];
#pragma unroll
    for (int i = 0; i < 4; i++) { ww[i] = f2bf(v0[i]); ww[4 + i] = f2bf(v1[i]); }
    *(uint4*)(Wb + which * 65536 + off) = *(uint4*)ww;
}

// ---------------- token index prep (parallel; int32/int64 vote) ----------------
__global__ __launch_bounds__(256) void tok_prep(const void* xraw, int* tokidx) {
    const long long* x64 = (const long long*)xraw;
    const int*       x32 = (const int*)xraw;
    long long probe = x64[threadIdx.x & 63];
    int ok = (probe >= 0 && probe < VOCAB) ? 1 : 0;
    int is64 = __all(ok);
    int i = blockIdx.x * 256 + threadIdx.x;
    int v = is64 ? (int)x64[i] : x32[i];
    tokidx[i] = (v < 0) ? 0 : ((v >= VOCAB) ? (VOCAB - 1) : v);
}

// ---------------- Kernel A: h build + one-matrix projection per block ----------------
__global__ __launch_bounds__(256) void qkv_kernel(
    const int* __restrict__ tokidx,
    const float* __restrict__ tok, const float* __restrict__ pos,
    const u16* __restrict__ Wb,
    const float* __restrict__ bqp, const float* __restrict__ bkp,
    const float* __restrict__ bvp,
    u16* __restrict__ Qg, u16* __restrict__ Kg, u16* __restrict__ Vt)
{
    __shared__ u16 h_lds[64 * 256];

    const int tid   = threadIdx.x;
    const int which = blockIdx.x >> 8;               // 0=Q 1=K 2=V
    const int t0    = (blockIdx.x & 255) * 64;
    const int bb    = t0 >> 11;
    const int tl0   = t0 & (TWIN - 1);

#pragma unroll
    for (int j = 0; j < 8; j++) {
        int c   = tid + 256 * j;
        int row = c >> 5, col = c & 31;
        int t   = t0 + row;
        int xi  = tokidx[t];
        const float* tp = tok + (size_t)xi * NEMB + col * 8;
        const float* pp = pos + (size_t)(t & (TWIN - 1)) * NEMB + col * 8;
        f4 a0 = *(const f4*)tp, a1 = *(const f4*)(tp + 4);
        f4 b0 = *(const f4*)pp, b1 = *(const f4*)(pp + 4);
        u16 hh[8];
#pragma unroll
        for (int i = 0; i < 4; i++) {
            hh[i]     = f2bf(a0[i] + b0[i]);
            hh[4 + i] = f2bf(a1[i] + b1[i]);
        }
        *(uint4*)((char*)h_lds + row * 512 + ((col * 16) ^ ((row & 7) << 4))) = *(uint4*)hh;
    }
    __syncthreads();

    const int wid = tid >> 6, lane = tid & 63, g = lane >> 4, lr = lane & 15;
    const u16* Wp = Wb + which * 65536;
    const float* Bp = (which == 0) ? bqp : ((which == 1) ? bkp : bvp);

    f32x4 acc[16];
#pragma unroll
    for (int i = 0; i < 16; i++) acc[i] = (f32x4){0.f, 0.f, 0.f, 0.f};

#pragma unroll
    for (int es = 0; es < 8; es++) {
        int arow = wid * 16 + lr;
        s16x8 af = *(const s16x8*)((const char*)h_lds + arow * 512 +
                                   ((es * 64 + g * 16) ^ ((arow & 7) << 4)));
        s16x8 bfv[16];
#pragma unroll
        for (int ct = 0; ct < 16; ct++)
            bfv[ct] = *(const s16x8*)(Wp + (size_t)(ct * 16 + lr) * NEMB + es * 32 + g * 8);
#pragma unroll
        for (int ct = 0; ct < 16; ct++)
            acc[ct] = __builtin_amdgcn_mfma_f32_16x16x32_bf16(af, bfv[ct], acc[ct], 0, 0, 0);
    }

    if (which < 2) {
        u16* dst = (which == 0) ? Qg : Kg;
        __syncthreads();
#pragma unroll
        for (int ct = 0; ct < 16; ct++) {
            float bias = Bp[ct * 16 + lr];
#pragma unroll
            for (int r = 0; r < 4; r++)
                h_lds[(wid * 16 + 4 * g + r) * 256 + ct * 16 + lr] = f2bf(acc[ct][r] + bias);
        }
        __syncthreads();
#pragma unroll
        for (int j = 0; j < 8; j++) {
            int c = tid + 256 * j;
            int row = c >> 5, col = c & 31;
            uint4 v = *(const uint4*)(h_lds + row * 256 + col * 8);
            *(uint4*)(dst + (size_t)(t0 + row) * NEMB + col * 8) = v;
        }
    } else {
#pragma unroll
        for (int ct = 0; ct < 16; ct++) {
            float bias = Bp[ct * 16 + lr];
            u16 pk[4];
#pragma unroll
            for (int r = 0; r < 4; r++) pk[r] = f2bf(acc[ct][r] + bias);
            int e = ct * 16 + lr;
            *(ushort4*)(Vt + ((size_t)bb * NEMB + e) * TWIN + tl0 + wid * 16 + 4 * g)
                = *(ushort4*)pk;
        }
    }
}

// ---------------- Kernel B: causal flash attention, DMA-pipelined ----------------
// 512 blocks x 128 thr (2 waves). KTILE=32. K/V double-buffered via global_load_lds
// (async DMA, linear dest + permuted source). One vmcnt(0)+barrier per tile.
__global__ __launch_bounds__(128) void attn_kernel(
    const u16* __restrict__ Qg, const u16* __restrict__ Kg,
    const u16* __restrict__ Vt, float* __restrict__ outp)
{
    __shared__ u16 k_lds[2][32 * 256];        // 2 x 16KB; rows 512B, src-XOR-swizzled
    __shared__ u16 v_lds[2][4 * 256 * 8];     // 2 x 16KB; [kchunk][e][8k], 16B rows

    const int tid = threadIdx.x;
    const int bid = blockIdx.x;
    const int bb  = bid & 7;
    const int idx = bid >> 3;
    const int qtile = (idx < 32) ? (63 - idx) : (idx - 32);   // pair-balanced
    const int q0 = qtile * 32;
    const int nt = qtile + 1;

    const u16* Qb = Qg + (size_t)bb * TWIN * NEMB;
    const u16* Kb = Kg + (size_t)bb * TWIN * NEMB;
    const u16* Vb = Vt + (size_t)bb * NEMB * TWIN;
    float* Ob = outp + (size_t)bb * TWIN * NEMB;

    const int wid = tid >> 6, lane = tid & 63;
    const int q   = lane & 15, hi = lane >> 4;
    const int qrow = q0 + wid * 16 + q;

    s16x8 qf[8];
#pragma unroll
    for (int es = 0; es < 8; es++)
        qf[es] = *(const s16x8*)(Qb + (size_t)qrow * NEMB + es * 32 + hi * 8);

    f32x4 o[16];
#pragma unroll
    for (int i = 0; i < 16; i++) o[i] = (f32x4){0.f, 0.f, 0.f, 0.f};
    float m = -1.0e4f, l = 0.f;

    // DMA stage of one K/V tile into buffer p. Wave w issues chunks w*8..w*8+7;
    // each chunk: 64 lanes x 16B -> LDS base+lane*16 (linear). Sources permuted.
    #define STAGE_TILE(p, kbase_)                                                     \
    {                                                                                 \
        const int kb_ = (kbase_);                                                     \
        _Pragma("unroll")                                                             \
        for (int i = 0; i < 8; i++) {                                                 \
            int gc = wid * 8 + i;                                                     \
            int s  = gc * 64 + lane;                                                  \
            int row = s >> 5, col16 = s & 31;                                         \
            const char* ksrc = (const char*)(Kb + (size_t)(kb_ + row) * NEMB)         \
                               + ((col16 * 16) ^ ((row & 7) << 4));                   \
            gload_lds16(ksrc, (char*)k_lds[p] + gc * 1024);                           \
            int rr = s >> 8, ee = s & 255;                                            \
            const char* vsrc = (const char*)(Vb + (size_t)ee * TWIN + kb_ + rr * 8);  \
            gload_lds16(vsrc, (char*)v_lds[p] + gc * 1024);                           \
        }                                                                             \
    }

    // prologue: tile 0 -> buf 0
    STAGE_TILE(0, 0)
    asm volatile("s_waitcnt vmcnt(0)" ::: "memory");
    __syncthreads();

    for (int t = 0; t < nt; t++) {
        const int kb = t * 32;
        const char* kbase = (const char*)k_lds[t & 1];
        const char* vbase = (const char*)v_lds[t & 1];

        // issue next tile's DMA (no register consumer -> cannot be sunk)
        if (t + 1 < nt) STAGE_TILE((t + 1) & 1, kb + 32)
        __builtin_amdgcn_sched_barrier(0);

        // S^T = K·Q^T (r7-verified core)
        f32x4 st0 = (f32x4){0.f, 0.f, 0.f, 0.f};
        f32x4 st1 = (f32x4){0.f, 0.f, 0.f, 0.f};
#pragma unroll
        for (int es = 0; es < 8; es++) {
            s16x8 kf0 = *(const s16x8*)(kbase + q * 512 +
                                        ((es * 64 + hi * 16) ^ ((q & 7) << 4)));
            st0 = __builtin_amdgcn_mfma_f32_16x16x32_bf16(kf0, qf[es], st0, 0, 0, 0);
            int row1 = q + 16;
            s16x8 kf1 = *(const s16x8*)(kbase + row1 * 512 +
                                        ((es * 64 + hi * 16) ^ ((row1 & 7) << 4)));
            st1 = __builtin_amdgcn_mfma_f32_16x16x32_bf16(kf1, qf[es], st1, 0, 0, 0);
        }

        // causal mask (diagonal tile only)
        if (t == nt - 1) {
#pragma unroll
            for (int r = 0; r < 4; r++) {
                if (kb + 4 * hi + r > qrow)      st0[r] = -1.0e4f;
                if (kb + 16 + 4 * hi + r > qrow) st1[r] = -1.0e4f;
            }
        }

        // in-register softmax (2 shfl cross-hi)
        float tm = fmaxf(fmaxf(fmaxf(st0[0], st0[1]), fmaxf(st0[2], st0[3])),
                         fmaxf(fmaxf(st1[0], st1[1]), fmaxf(st1[2], st1[3])));
        tm = fmaxf(tm, __shfl_xor(tm, 16));
        tm = fmaxf(tm, __shfl_xor(tm, 32));
        if (__any(tm > m)) {
            float mn = fmaxf(m, tm);
            float sc = __expf(m - mn);
            m = mn; l *= sc;
            float scr[4];
#pragma unroll
            for (int r = 0; r < 4; r++) scr[r] = __shfl(sc, hi * 20 + r);
#pragma unroll
            for (int et = 0; et < 16; et++)
#pragma unroll
                for (int r = 0; r < 4; r++) o[et][r] *= scr[r];
        }
        float p0[4], p1[4];
#pragma unroll
        for (int r = 0; r < 4; r++) {
            p0[r] = __expf(st0[r] - m);
            p1[r] = __expf(st1[r] - m);
        }
        float rs = (p0[0] + p0[1]) + (p0[2] + p0[3]) + (p1[0] + p1[1]) + (p1[2] + p1[3]);
        rs += __shfl_xor(rs, 16);
        rs += __shfl_xor(rs, 32);
        l += rs;

        // P -> A-frag relayout in-register (8 shfl + select)
        u32 pk00 = pack2bf(p0[0], p0[1]), pk01 = pack2bf(p0[2], p0[3]);
        u32 pk10 = pack2bf(p1[0], p1[1]), pk11 = pack2bf(p1[2], p1[3]);
        int sA = (lane & 15) | ((lane & 16) << 1);
        int sB = sA + 16;
        u32 b00 = (u32)__shfl((int)pk00, sA), b01 = (u32)__shfl((int)pk01, sA);
        u32 b02 = (u32)__shfl((int)pk00, sB), b03 = (u32)__shfl((int)pk01, sB);
        u32 b10 = (u32)__shfl((int)pk10, sA), b11 = (u32)__shfl((int)pk11, sA);
        u32 b12 = (u32)__shfl((int)pk10, sB), b13 = (u32)__shfl((int)pk11, sB);
        bool c1 = (hi & 2) != 0;
        union { uint4 u; s16x8 v; } pu;
        pu.u.x = c1 ? b10 : b00;
        pu.u.y = c1 ? b11 : b01;
        pu.u.z = c1 ? b12 : b02;
        pu.u.w = c1 ? b13 : b03;
        s16x8 pf = pu.v;

        // O += P V : region hi holds k-chunk hi*8..+7; row e = q+16et (16B rows)
#pragma unroll
        for (int et = 0; et < 16; et++) {
            s16x8 vf = *(const s16x8*)(vbase + hi * 4096 + (q + 16 * et) * 16);
            o[et] = __builtin_amdgcn_mfma_f32_16x16x32_bf16(pf, vf, o[et], 0, 0, 0);
        }

        // drain next-tile DMA (mostly complete by now) + readers done
        asm volatile("s_waitcnt vmcnt(0)" ::: "memory");
        __syncthreads();
    }
    #undef STAGE_TILE

    // epilogue: per-row 1/l via shfl, direct fp32 stores
    float rinv = 1.0f / l;
    float invr[4];
#pragma unroll
    for (int r = 0; r < 4; r++) invr[r] = __shfl(rinv, hi * 20 + r);
#pragma unroll
    for (int et = 0; et < 16; et++) {
#pragma unroll
        for (int r = 0; r < 4; r++)
            Ob[(size_t)(q0 + wid * 16 + 4 * hi + r) * NEMB + q + 16 * et]
                = o[et][r] * invr[r];
    }
}

// ---------------- ws-too-small diagnostic ----------------
__global__ __launch_bounds__(256) void ws_diag(float* outp, int n, float val) {
    int i = blockIdx.x * 256 + threadIdx.x;
    if (i < n) outp[i] = (i == 0) ? val : 0.0f;
}

extern "C" void kernel_launch(void* const* d_in, const int* in_sizes, int n_in,
                              void* d_out, int out_size, void* d_ws, size_t ws_size,
                              hipStream_t stream)
{
    const void*  x   = d_in[0];
    const float* tok = (const float*)d_in[1];
    const float* pos = (const float*)d_in[2];
    const float* Wq  = (const float*)d_in[3];
    const float* bq  = (const float*)d_in[4];
    const float* Wk  = (const float*)d_in[5];
    const float* bk  = (const float*)d_in[6];
    const float* Wv  = (const float*)d_in[7];
    const float* bv  = (const float*)d_in[8];

    const size_t kvElems = (size_t)NB * TWIN * NEMB;
    const size_t need = 3 * kvElems * 2 + 3 * 65536 * 2 + NTOK * 4 + 64;

    if (ws_size < need) {
        float val = 1000.0f + (float)(ws_size >> 20);
        hipLaunchKernelGGL(ws_diag, dim3((out_size + 255) / 256), dim3(256), 0, stream,
                           (float*)d_out, out_size, val);
        return;
    }

    u16* Qg = (u16*)d_ws;
    u16* Kg = Qg + kvElems;
    u16* Vt = Kg + kvElems;
    u16* Wb = Vt + kvElems;
    int* tokidx = (int*)(Wb + 3 * 65536);

    hipLaunchKernelGGL(wconv_kernel, dim3(96), dim3(256), 0, stream, Wq, Wk, Wv, Wb);
    hipLaunchKernelGGL(tok_prep, dim3(64), dim3(256), 0, stream, x, tokidx);
    hipLaunchKernelGGL(qkv_kernel, dim3(768), dim3(256), 0, stream,
                       tokidx, tok, pos, Wb, bq, bk, bv, Qg, Kg, Vt);
    hipLaunchKernelGGL(attn_kernel, dim3(512), dim3(128), 0, stream,
                       Qg, Kg, Vt, (float*)d_out);
}

// Round 11
// 176.540 us; speedup vs baseline: 1.5223x; 1.1936x over previous
//
#include <hip/hip_runtime.h>

// MiniGPT fused forward. Inputs fp32 (x int32/int64 auto), OUTPUT fp32 (proven r5).
// R11: barrier-free attention. Each wave independent: own 16 q-rows, own K dbuf LDS
// (staged by itself via global_load_lds), V in regs via asm-pinned global_load_dwordx4,
// counted vmcnt (never 0 mid-loop), sched_barrier(0) after waits (rule 18). ZERO
// __syncthreads in the k-loop (r7/r9/r10 lesson: any block lockstep + drain = ~4500cy/tile).
// Counted-wait safety: wait targets are always the oldest outstanding ops, so unexpected
// extra vmem (spills) only over-waits, never breaks correctness.
// qkv (768 blocks), tok_prep, wconv unchanged. ws layout unchanged (~24.6MB, guarded).

#define TWIN 2048
#define NEMB 256
#define NB   8
#define VOCAB 50257
#define NTOK (NB * TWIN)

typedef __attribute__((ext_vector_type(8))) short s16x8;
typedef __attribute__((ext_vector_type(4))) float f32x4;
typedef __attribute__((ext_vector_type(4))) float f4;
typedef unsigned short u16;
typedef unsigned int   u32;

__device__ __forceinline__ u16 f2bf(float f) {
    union { float f; u32 i; } x; x.f = f;
    u32 r = x.i + 0x7fffu + ((x.i >> 16) & 1u);
    return (u16)(r >> 16);
}
__device__ __forceinline__ u32 pack2bf(float a, float b) {
    return (u32)f2bf(a) | ((u32)f2bf(b) << 16);
}
__device__ __forceinline__ void gload_lds16(const void* g, void* l) {
    __builtin_amdgcn_global_load_lds(
        (const __attribute__((address_space(1))) void*)g,
        (__attribute__((address_space(3))) void*)l, 16, 0, 0);
}

// ---------------- W fp32 -> bf16, once ----------------
__global__ __launch_bounds__(256) void wconv_kernel(
    const float* __restrict__ Wq, const float* __restrict__ Wk,
    const float* __restrict__ Wv, u16* __restrict__ Wb)
{
    int b = blockIdx.x;
    int which = b >> 5;
    int off = (b & 31) * 2048 + threadIdx.x * 8;
    const float* src = (which == 0) ? Wq : ((which == 1) ? Wk : Wv);
    f4 v0 = *(const f4*)(src + off);
    f4 v1 = *(const f4*)(src + off + 4);
    u16 ww[8];
#pragma unroll
    for (int i = 0; i < 4; i++) { ww[i] = f2bf(v0[i]); ww[4 + i] = f2bf(v1[i]); }
    *(uint4*)(Wb + which * 65536 + off) = *(uint4*)ww;
}

// ---------------- token index prep (parallel; int32/int64 vote) ----------------
__global__ __launch_bounds__(256) void tok_prep(const void* xraw, int* tokidx) {
    const long long* x64 = (const long long*)xraw;
    const int*       x32 = (const int*)xraw;
    long long probe = x64[threadIdx.x & 63];
    int ok = (probe >= 0 && probe < VOCAB) ? 1 : 0;
    int is64 = __all(ok);
    int i = blockIdx.x * 256 + threadIdx.x;
    int v = is64 ? (int)x64[i] : x32[i];
    tokidx[i] = (v < 0) ? 0 : ((v >= VOCAB) ? (VOCAB - 1) : v);
}

// ---------------- Kernel A: h build + one-matrix projection per block ----------------
__global__ __launch_bounds__(256) void qkv_kernel(
    const int* __restrict__ tokidx,
    const float* __restrict__ tok, const float* __restrict__ pos,
    const u16* __restrict__ Wb,
    const float* __restrict__ bqp, const float* __restrict__ bkp,
    const float* __restrict__ bvp,
    u16* __restrict__ Qg, u16* __restrict__ Kg, u16* __restrict__ Vt)
{
    __shared__ u16 h_lds[64 * 256];

    const int tid   = threadIdx.x;
    const int which = blockIdx.x >> 8;               // 0=Q 1=K 2=V
    const int t0    = (blockIdx.x & 255) * 64;
    const int bb    = t0 >> 11;
    const int tl0   = t0 & (TWIN - 1);

#pragma unroll
    for (int j = 0; j < 8; j++) {
        int c   = tid + 256 * j;
        int row = c >> 5, col = c & 31;
        int t   = t0 + row;
        int xi  = tokidx[t];
        const float* tp = tok + (size_t)xi * NEMB + col * 8;
        const float* pp = pos + (size_t)(t & (TWIN - 1)) * NEMB + col * 8;
        f4 a0 = *(const f4*)tp, a1 = *(const f4*)(tp + 4);
        f4 b0 = *(const f4*)pp, b1 = *(const f4*)(pp + 4);
        u16 hh[8];
#pragma unroll
        for (int i = 0; i < 4; i++) {
            hh[i]     = f2bf(a0[i] + b0[i]);
            hh[4 + i] = f2bf(a1[i] + b1[i]);
        }
        *(uint4*)((char*)h_lds + row * 512 + ((col * 16) ^ ((row & 7) << 4))) = *(uint4*)hh;
    }
    __syncthreads();

    const int wid = tid >> 6, lane = tid & 63, g = lane >> 4, lr = lane & 15;
    const u16* Wp = Wb + which * 65536;
    const float* Bp = (which == 0) ? bqp : ((which == 1) ? bkp : bvp);

    f32x4 acc[16];
#pragma unroll
    for (int i = 0; i < 16; i++) acc[i] = (f32x4){0.f, 0.f, 0.f, 0.f};

#pragma unroll
    for (int es = 0; es < 8; es++) {
        int arow = wid * 16 + lr;
        s16x8 af = *(const s16x8*)((const char*)h_lds + arow * 512 +
                                   ((es * 64 + g * 16) ^ ((arow & 7) << 4)));
        s16x8 bfv[16];
#pragma unroll
        for (int ct = 0; ct < 16; ct++)
            bfv[ct] = *(const s16x8*)(Wp + (size_t)(ct * 16 + lr) * NEMB + es * 32 + g * 8);
#pragma unroll
        for (int ct = 0; ct < 16; ct++)
            acc[ct] = __builtin_amdgcn_mfma_f32_16x16x32_bf16(af, bfv[ct], acc[ct], 0, 0, 0);
    }

    if (which < 2) {
        u16* dst = (which == 0) ? Qg : Kg;
        __syncthreads();
#pragma unroll
        for (int ct = 0; ct < 16; ct++) {
            float bias = Bp[ct * 16 + lr];
#pragma unroll
            for (int r = 0; r < 4; r++)
                h_lds[(wid * 16 + 4 * g + r) * 256 + ct * 16 + lr] = f2bf(acc[ct][r] + bias);
        }
        __syncthreads();
#pragma unroll
        for (int j = 0; j < 8; j++) {
            int c = tid + 256 * j;
            int row = c >> 5, col = c & 31;
            uint4 v = *(const uint4*)(h_lds + row * 256 + col * 8);
            *(uint4*)(dst + (size_t)(t0 + row) * NEMB + col * 8) = v;
        }
    } else {
#pragma unroll
        for (int ct = 0; ct < 16; ct++) {
            float bias = Bp[ct * 16 + lr];
            u16 pk[4];
#pragma unroll
            for (int r = 0; r < 4; r++) pk[r] = f2bf(acc[ct][r] + bias);
            int e = ct * 16 + lr;
            *(ushort4*)(Vt + ((size_t)bb * NEMB + e) * TWIN + tl0 + wid * 16 + 4 * g)
                = *(ushort4*)pk;
        }
    }
}

// ---------------- Kernel B: barrier-free flash attention ----------------
// 512 blocks x 128 thr = 2 INDEPENDENT waves. Per wave: 16 q-rows, private K dbuf
// (2x16KB LDS, global_load_lds), V in regs (asm-pinned loads), counted vmcnt.
__global__ __launch_bounds__(128) void attn_kernel(
    const u16* __restrict__ Qg, const u16* __restrict__ Kg,
    const u16* __restrict__ Vt, float* __restrict__ outp)
{
    __shared__ u16 k_lds[2][2][32 * 256];   // [wave][buf], 64KB total

    const int tid = threadIdx.x;
    const int bid = blockIdx.x;
    const int bb  = bid & 7;
    const int idx = bid >> 3;
    const int qtile = (idx < 32) ? (63 - idx) : (idx - 32);   // pair-balanced
    const int q0 = qtile * 32;
    const int nt = qtile + 1;

    const u16* Qb = Qg + (size_t)bb * TWIN * NEMB;
    const u16* Kb = Kg + (size_t)bb * TWIN * NEMB;
    const u16* Vb = Vt + (size_t)bb * NEMB * TWIN;
    float* Ob = outp + (size_t)bb * TWIN * NEMB;

    const int wid = tid >> 6, lane = tid & 63;
    const int q   = lane & 15, hi = lane >> 4;
    const int qrow = q0 + wid * 16 + q;

    // Q rows in regs (oldest vmem; drained by first counted wait)
    s16x8 qf[8];
#pragma unroll
    for (int es = 0; es < 8; es++)
        qf[es] = *(const s16x8*)(Qb + (size_t)qrow * NEMB + es * 32 + hi * 8);

    char* kb0 = (char*)&k_lds[wid][0][0];
    char* kb1 = (char*)&k_lds[wid][1][0];

    // wave-private K tile stage: 16 chunks x (64 lanes x 16B), source-XOR-swizzled
    #define KSTAGE(dst_, kb_)                                                         \
    {                                                                                 \
        const int kbq_ = (kb_);                                                       \
        _Pragma("unroll")                                                             \
        for (int gc = 0; gc < 16; gc++) {                                             \
            int s = gc * 64 + lane;                                                   \
            int row = s >> 5, col16 = s & 31;                                         \
            const char* src = (const char*)(Kb + (size_t)(kbq_ + row) * NEMB)         \
                              + ((col16 * 16) ^ ((row & 7) << 4));                    \
            gload_lds16(src, (dst_) + gc * 1024);                                     \
        }                                                                             \
    }

    KSTAGE(kb0, 0)     // prologue: K(0)

    f32x4 o[16];
#pragma unroll
    for (int i = 0; i < 16; i++) o[i] = (f32x4){0.f, 0.f, 0.f, 0.f};
    float m = -1.0e4f, l = 0.f;

    for (int t = 0; t < nt; t++) {
        const int kb = t * 32;
        const char* kcur = (t & 1) ? kb1 : kb0;
        char*       knxt = (t & 1) ? kb0 : kb1;

        // (1) V(t) fragment loads -> regs, asm-pinned (cannot be sunk)
        uint4 vf[16];
        {
            unsigned long long va =
                (unsigned long long)(Vb + (size_t)q * TWIN + kb + hi * 8);
#pragma unroll
            for (int et = 0; et < 16; et++) {
                asm volatile("global_load_dwordx4 %0, %1, off"
                             : "=&v"(vf[et]) : "v"(va) : "memory");
                va += (unsigned long long)16 * TWIN * 2;
            }
        }
        // (2) K(t+1) DMA into other buffer
        if (t + 1 < nt) KSTAGE(knxt, kb + 32)

        // (3) wait K(t) ready (issued a full tile ago). Targets are oldest ops.
        if (t + 1 < nt) asm volatile("s_waitcnt vmcnt(32)" ::: "memory");
        else            asm volatile("s_waitcnt vmcnt(16)" ::: "memory");
        __builtin_amdgcn_sched_barrier(0);

        // S^T = K·Q^T (r7-verified core)
        f32x4 st0 = (f32x4){0.f, 0.f, 0.f, 0.f};
        f32x4 st1 = (f32x4){0.f, 0.f, 0.f, 0.f};
#pragma unroll
        for (int es = 0; es < 8; es++) {
            s16x8 kf0 = *(const s16x8*)(kcur + q * 512 +
                                        ((es * 64 + hi * 16) ^ ((q & 7) << 4)));
            st0 = __builtin_amdgcn_mfma_f32_16x16x32_bf16(kf0, qf[es], st0, 0, 0, 0);
            int row1 = q + 16;
            s16x8 kf1 = *(const s16x8*)(kcur + row1 * 512 +
                                        ((es * 64 + hi * 16) ^ ((row1 & 7) << 4)));
            st1 = __builtin_amdgcn_mfma_f32_16x16x32_bf16(kf1, qf[es], st1, 0, 0, 0);
        }

        // causal mask (diagonal tile only)
        if (t == nt - 1) {
#pragma unroll
            for (int r = 0; r < 4; r++) {
                if (kb + 4 * hi + r > qrow)      st0[r] = -1.0e4f;
                if (kb + 16 + 4 * hi + r > qrow) st1[r] = -1.0e4f;
            }
        }

        // in-register softmax (2 shfl cross-hi)
        float tm = fmaxf(fmaxf(fmaxf(st0[0], st0[1]), fmaxf(st0[2], st0[3])),
                         fmaxf(fmaxf(st1[0], st1[1]), fmaxf(st1[2], st1[3])));
        tm = fmaxf(tm, __shfl_xor(tm, 16));
        tm = fmaxf(tm, __shfl_xor(tm, 32));
        if (__any(tm > m)) {
            float mn = fmaxf(m, tm);
            float sc = __expf(m - mn);
            m = mn; l *= sc;
            float scr[4];
#pragma unroll
            for (int r = 0; r < 4; r++) scr[r] = __shfl(sc, hi * 20 + r);
#pragma unroll
            for (int et = 0; et < 16; et++)
#pragma unroll
                for (int r = 0; r < 4; r++) o[et][r] *= scr[r];
        }
        float p0[4], p1[4];
#pragma unroll
        for (int r = 0; r < 4; r++) {
            p0[r] = __expf(st0[r] - m);
            p1[r] = __expf(st1[r] - m);
        }
        float rs = (p0[0] + p0[1]) + (p0[2] + p0[3]) + (p1[0] + p1[1]) + (p1[2] + p1[3]);
        rs += __shfl_xor(rs, 16);
        rs += __shfl_xor(rs, 32);
        l += rs;

        // P -> A-frag relayout in-register (8 shfl + select)
        u32 pk00 = pack2bf(p0[0], p0[1]), pk01 = pack2bf(p0[2], p0[3]);
        u32 pk10 = pack2bf(p1[0], p1[1]), pk11 = pack2bf(p1[2], p1[3]);
        int sA = (lane & 15) | ((lane & 16) << 1);
        int sB = sA + 16;
        u32 b00 = (u32)__shfl((int)pk00, sA), b01 = (u32)__shfl((int)pk01, sA);
        u32 b02 = (u32)__shfl((int)pk00, sB), b03 = (u32)__shfl((int)pk01, sB);
        u32 b10 = (u32)__shfl((int)pk10, sA), b11 = (u32)__shfl((int)pk11, sA);
        u32 b12 = (u32)__shfl((int)pk10, sB), b13 = (u32)__shfl((int)pk11, sB);
        bool c1 = (hi & 2) != 0;
        union { uint4 u; s16x8 v; } pu;
        pu.u.x = c1 ? b10 : b00;
        pu.u.y = c1 ? b11 : b01;
        pu.u.z = c1 ? b12 : b02;
        pu.u.w = c1 ? b13 : b03;
        s16x8 pf = pu.v;

        // (4) wait V(t) (K(t+1) stays in flight -- counted, never 0 mid-loop)
        if (t + 1 < nt) asm volatile("s_waitcnt vmcnt(16)" ::: "memory");
        else            asm volatile("s_waitcnt vmcnt(0)"  ::: "memory");
        __builtin_amdgcn_sched_barrier(0);

        // (5) O += P V from registers
#pragma unroll
        for (int et = 0; et < 16; et++) {
            union { uint4 u; s16x8 v; } vu; vu.u = vf[et];
            o[et] = __builtin_amdgcn_mfma_f32_16x16x32_bf16(pf, vu.v, o[et], 0, 0, 0);
        }
    }
    #undef KSTAGE

    // epilogue: per-row 1/l via shfl, direct fp32 stores
    float rinv = 1.0f / l;
    float invr[4];
#pragma unroll
    for (int r = 0; r < 4; r++) invr[r] = __shfl(rinv, hi * 20 + r);
#pragma unroll
    for (int et = 0; et < 16; et++) {
#pragma unroll
        for (int r = 0; r < 4; r++)
            Ob[(size_t)(q0 + wid * 16 + 4 * hi + r) * NEMB + q + 16 * et]
                = o[et][r] * invr[r];
    }
}

// ---------------- ws-too-small diagnostic ----------------
__global__ __launch_bounds__(256) void ws_diag(float* outp, int n, float val) {
    int i = blockIdx.x * 256 + threadIdx.x;
    if (i < n) outp[i] = (i == 0) ? val : 0.0f;
}

extern "C" void kernel_launch(void* const* d_in, const int* in_sizes, int n_in,
                              void* d_out, int out_size, void* d_ws, size_t ws_size,
                              hipStream_t stream)
{
    const void*  x   = d_in[0];
    const float* tok = (const float*)d_in[1];
    const float* pos = (const float*)d_in[2];
    const float* Wq  = (const float*)d_in[3];
    const float* bq  = (const float*)d_in[4];
    const float* Wk  = (const float*)d_in[5];
    const float* bk  = (const float*)d_in[6];
    const float* Wv  = (const float*)d_in[7];
    const float* bv  = (const float*)d_in[8];

    const size_t kvElems = (size_t)NB * TWIN * NEMB;
    const size_t need = 3 * kvElems * 2 + 3 * 65536 * 2 + NTOK * 4 + 64;

    if (ws_size < need) {
        float val = 1000.0f + (float)(ws_size >> 20);
        hipLaunchKernelGGL(ws_diag, dim3((out_size + 255) / 256), dim3(256), 0, stream,
                           (float*)d_out, out_size, val);
        return;
    }

    u16* Qg = (u16*)d_ws;
    u16* Kg = Qg + kvElems;
    u16* Vt = Kg + kvElems;
    u16* Wb = Vt + kvElems;
    int* tokidx = (int*)(Wb + 3 * 65536);

    hipLaunchKernelGGL(wconv_kernel, dim3(96), dim3(256), 0, stream, Wq, Wk, Wv, Wb);
    hipLaunchKernelGGL(tok_prep, dim3(64), dim3(256), 0, stream, x, tokidx);
    hipLaunchKernelGGL(qkv_kernel, dim3(768), dim3(256), 0, stream,
                       tokidx, tok, pos, Wb, bq, bk, bv, Qg, Kg, Vt);
    hipLaunchKernelGGL(attn_kernel, dim3(512), dim3(128), 0, stream,
                       Qg, Kg, Vt, (float*)d_out);
}

// Round 12
// 160.567 us; speedup vs baseline: 1.6737x; 1.0995x over previous
//
#include <hip/hip_runtime.h>

// MiniGPT fused forward. Inputs fp32 (x int32/int64 auto), OUTPUT fp32 (proven r5).
// R12: flash-decoding split-K. (b,qtile) -> <=2 chunks of <=32 tiles; 768 blocks,
// heavy-first; chunks write unnormalized partials (O bf16, m/l fp32) to ws; combine
// kernel merges exactly and writes all d_out. Q lives in d_out (bf16) during attn.
// K shared triple-buffer LDS (48KB, 3 blk/CU), counted vmcnt (never 0 mid-loop),
// 1 barrier/tile; V -> regs via asm-pinned loads (r11-verified pattern).
// Fallback: if ws_size < split need, run r11 barrier-free attn (Q in ws).
// qkv: 32-row blocks, grid 1536, 16KB LDS (~6 blk/CU TLP). r11 ledger: wall == one
// block's 64-tile serial chain -> shorten the chain, add resident waves.

#define TWIN 2048
#define NEMB 256
#define NB   8
#define VOCAB 50257
#define NTOK (NB * TWIN)

typedef __attribute__((ext_vector_type(8))) short s16x8;
typedef __attribute__((ext_vector_type(4))) float f32x4;
typedef __attribute__((ext_vector_type(4))) float f4;
typedef unsigned short u16;
typedef unsigned int   u32;

__device__ __forceinline__ u16 f2bf(float f) {
    union { float f; u32 i; } x; x.f = f;
    u32 r = x.i + 0x7fffu + ((x.i >> 16) & 1u);
    return (u16)(r >> 16);
}
__device__ __forceinline__ float bf2f(u16 u) {
    union { u32 i; float f; } x; x.i = ((u32)u) << 16; return x.f;
}
__device__ __forceinline__ u32 pack2bf(float a, float b) {
    return (u32)f2bf(a) | ((u32)f2bf(b) << 16);
}
__device__ __forceinline__ void gload_lds16(const void* g, void* l) {
    __builtin_amdgcn_global_load_lds(
        (const __attribute__((address_space(1))) void*)g,
        (__attribute__((address_space(3))) void*)l, 16, 0, 0);
}

// ---------------- W fp32 -> bf16, once ----------------
__global__ __launch_bounds__(256) void wconv_kernel(
    const float* __restrict__ Wq, const float* __restrict__ Wk,
    const float* __restrict__ Wv, u16* __restrict__ Wb)
{
    int b = blockIdx.x;
    int which = b >> 5;
    int off = (b & 31) * 2048 + threadIdx.x * 8;
    const float* src = (which == 0) ? Wq : ((which == 1) ? Wk : Wv);
    f4 v0 = *(const f4*)(src + off);
    f4 v1 = *(const f4*)(src + off + 4);
    u16 ww[8];
#pragma unroll
    for (int i = 0; i < 4; i++) { ww[i] = f2bf(v0[i]); ww[4 + i] = f2bf(v1[i]); }
    *(uint4*)(Wb + which * 65536 + off) = *(uint4*)ww;
}

// ---------------- token index prep ----------------
__global__ __launch_bounds__(256) void tok_prep(const void* xraw, int* tokidx) {
    const long long* x64 = (const long long*)xraw;
    const int*       x32 = (const int*)xraw;
    long long probe = x64[threadIdx.x & 63];
    int ok = (probe >= 0 && probe < VOCAB) ? 1 : 0;
    int is64 = __all(ok);
    int i = blockIdx.x * 256 + threadIdx.x;
    int v = is64 ? (int)x64[i] : x32[i];
    tokidx[i] = (v < 0) ? 0 : ((v >= VOCAB) ? (VOCAB - 1) : v);
}

// ---------------- Kernel A: h build + projection, 32 rows/block ----------------
// grid 1536 = 3 matrices x 512 t-blocks. 128 thr (2 waves). 16KB LDS -> high TLP.
__global__ __launch_bounds__(128) void qkv_kernel(
    const int* __restrict__ tokidx,
    const float* __restrict__ tok, const float* __restrict__ pos,
    const u16* __restrict__ Wb,
    const float* __restrict__ bqp, const float* __restrict__ bkp,
    const float* __restrict__ bvp,
    u16* __restrict__ Qg, u16* __restrict__ Kg, u16* __restrict__ Vt)
{
    __shared__ u16 h_lds[32 * 256];     // 16KB: h (swizzled), then out staging

    const int tid   = threadIdx.x;
    const int which = blockIdx.x >> 9;              // 0=Q 1=K 2=V
    const int t0    = (blockIdx.x & 511) * 32;
    const int bb    = t0 >> 11;
    const int tl0   = t0 & (TWIN - 1);

#pragma unroll
    for (int j = 0; j < 8; j++) {
        int c   = tid + 128 * j;                    // 1024 chunks of 8 elems
        int row = c >> 5, col = c & 31;
        int t   = t0 + row;
        int xi  = tokidx[t];
        const float* tp = tok + (size_t)xi * NEMB + col * 8;
        const float* pp = pos + (size_t)(t & (TWIN - 1)) * NEMB + col * 8;
        f4 a0 = *(const f4*)tp, a1 = *(const f4*)(tp + 4);
        f4 b0 = *(const f4*)pp, b1 = *(const f4*)(pp + 4);
        u16 hh[8];
#pragma unroll
        for (int i = 0; i < 4; i++) {
            hh[i]     = f2bf(a0[i] + b0[i]);
            hh[4 + i] = f2bf(a1[i] + b1[i]);
        }
        *(uint4*)((char*)h_lds + row * 512 + ((col * 16) ^ ((row & 7) << 4))) = *(uint4*)hh;
    }
    __syncthreads();

    const int wid = tid >> 6, lane = tid & 63, g = lane >> 4, lr = lane & 15;
    const u16* Wp = Wb + which * 65536;
    const float* Bp = (which == 0) ? bqp : ((which == 1) ? bkp : bvp);

    f32x4 acc[16];
#pragma unroll
    for (int i = 0; i < 16; i++) acc[i] = (f32x4){0.f, 0.f, 0.f, 0.f};

#pragma unroll
    for (int es = 0; es < 8; es++) {
        int arow = wid * 16 + lr;
        s16x8 af = *(const s16x8*)((const char*)h_lds + arow * 512 +
                                   ((es * 64 + g * 16) ^ ((arow & 7) << 4)));
        s16x8 bfv[16];
#pragma unroll
        for (int ct = 0; ct < 16; ct++)
            bfv[ct] = *(const s16x8*)(Wp + (size_t)(ct * 16 + lr) * NEMB + es * 32 + g * 8);
#pragma unroll
        for (int ct = 0; ct < 16; ct++)
            acc[ct] = __builtin_amdgcn_mfma_f32_16x16x32_bf16(af, bfv[ct], acc[ct], 0, 0, 0);
    }

    if (which < 2) {
        u16* dst = (which == 0) ? Qg : Kg;
        __syncthreads();                            // all h reads done; reuse h_lds
#pragma unroll
        for (int ct = 0; ct < 16; ct++) {
            float bias = Bp[ct * 16 + lr];
#pragma unroll
            for (int r = 0; r < 4; r++)
                h_lds[(wid * 16 + 4 * g + r) * 256 + ct * 16 + lr] = f2bf(acc[ct][r] + bias);
        }
        __syncthreads();
#pragma unroll
        for (int j = 0; j < 8; j++) {
            int c = tid + 128 * j;
            int row = c >> 5, col = c & 31;
            uint4 v = *(const uint4*)(h_lds + row * 256 + col * 8);
            *(uint4*)(dst + (size_t)(t0 + row) * NEMB + col * 8) = v;
        }
    } else {
#pragma unroll
        for (int ct = 0; ct < 16; ct++) {
            float bias = Bp[ct * 16 + lr];
            u16 pk[4];
#pragma unroll
            for (int r = 0; r < 4; r++) pk[r] = f2bf(acc[ct][r] + bias);
            int e = ct * 16 + lr;
            *(ushort4*)(Vt + ((size_t)bb * NEMB + e) * TWIN + tl0 + wid * 16 + 4 * g)
                = *(ushort4*)pk;
        }
    }
}

// ---------------- Kernel B1: attn partial (split-K chunk) ----------------
// 768 blocks x 128 thr (2 waves). Chunk = up to 32 K-tiles of one (b,qtile).
// Shared K triple-buffer, counted vmcnt, 1 barrier/tile. Writes unnormalized
// partial O (bf16) + m,l (fp32). Heavy chunks dispatched first.
__global__ __launch_bounds__(128) void attn_partial(
    const u16* __restrict__ Qg, const u16* __restrict__ Kg,
    const u16* __restrict__ Vt, u16* __restrict__ Ppart,
    float* __restrict__ Pm, float* __restrict__ Pl)
{
    __shared__ u16 k_lds[3][32 * 256];     // 48KB

    const int tid = threadIdx.x;
    const int bid = blockIdx.x;
    const int bb  = bid & 7;
    const int idx = bid >> 3;                        // 0..95
    int qt, cc;
    if (idx < 64) { qt = 63 - idx; cc = 0; }         // heavy first
    else          { qt = 32 + (95 - idx); cc = 1; }
    const int ts = cc * 32;                          // first tile of chunk
    const int te = (qt + 1 < ts + 32) ? (qt + 1) : (ts + 32);
    const int n  = te - ts;                          // tiles in this chunk
    const int cid = bb * 96 + ((cc == 0) ? qt : (64 + qt - 32));

    const u16* Qb = Qg + (size_t)bb * TWIN * NEMB;
    const u16* Kb = Kg + (size_t)bb * TWIN * NEMB;
    const u16* Vb = Vt + (size_t)bb * NEMB * TWIN;

    const int wid = tid >> 6, lane = tid & 63;
    const int q   = lane & 15, hi = lane >> 4;
    const int qrow = qt * 32 + wid * 16 + q;

    s16x8 qf[8];
#pragma unroll
    for (int es = 0; es < 8; es++)
        qf[es] = *(const s16x8*)(Qb + (size_t)qrow * NEMB + es * 32 + hi * 8);

    // shared-buffer K stage: wave wid stages chunks wid*8..wid*8+7 (8 DMA/wave)
    #define KSTAGE(dst_, kb_)                                                         \
    {                                                                                 \
        const int kbq_ = (kb_);                                                       \
        _Pragma("unroll")                                                             \
        for (int i2 = 0; i2 < 8; i2++) {                                              \
            int gc = wid * 8 + i2;                                                    \
            int s = gc * 64 + lane;                                                   \
            int row = s >> 5, col16 = s & 31;                                         \
            const char* src = (const char*)(Kb + (size_t)(kbq_ + row) * NEMB)         \
                              + ((col16 * 16) ^ ((row & 7) << 4));                    \
            gload_lds16(src, (dst_) + gc * 1024);                                     \
        }                                                                             \
    }

    char* kcur = (char*)&k_lds[0][0];
    char* knx1 = (char*)&k_lds[1][0];
    char* knx2 = (char*)&k_lds[2][0];

    KSTAGE(kcur, ts * 32)
    if (n > 1) KSTAGE(knx1, (ts + 1) * 32)
    if (n > 1) asm volatile("s_waitcnt vmcnt(8)" ::: "memory");
    else       asm volatile("s_waitcnt vmcnt(0)" ::: "memory");
    __builtin_amdgcn_sched_barrier(0);
    __syncthreads();

    f32x4 o[16];
#pragma unroll
    for (int i = 0; i < 16; i++) o[i] = (f32x4){0.f, 0.f, 0.f, 0.f};
    float m = -1.0e4f, l = 0.f;

    for (int t = 0; t < n; t++) {
        const int kb = (ts + t) * 32;

        // V(t) -> regs, asm-pinned
        uint4 vf[16];
        {
            unsigned long long va =
                (unsigned long long)(Vb + (size_t)q * TWIN + kb + hi * 8);
#pragma unroll
            for (int et = 0; et < 16; et++) {
                asm volatile("global_load_dwordx4 %0, %1, off"
                             : "=&v"(vf[et]) : "v"(va) : "memory");
                va += (unsigned long long)16 * TWIN * 2;
            }
        }
        // K(t+2) DMA
        if (t + 2 < n) KSTAGE(knx2, kb + 64)

        // S^T = K·Q^T from kcur (ready + barriered)
        f32x4 st0 = (f32x4){0.f, 0.f, 0.f, 0.f};
        f32x4 st1 = (f32x4){0.f, 0.f, 0.f, 0.f};
#pragma unroll
        for (int es = 0; es < 8; es++) {
            s16x8 kf0 = *(const s16x8*)(kcur + q * 512 +
                                        ((es * 64 + hi * 16) ^ ((q & 7) << 4)));
            st0 = __builtin_amdgcn_mfma_f32_16x16x32_bf16(kf0, qf[es], st0, 0, 0, 0);
            int row1 = q + 16;
            s16x8 kf1 = *(const s16x8*)(kcur + row1 * 512 +
                                        ((es * 64 + hi * 16) ^ ((row1 & 7) << 4)));
            st1 = __builtin_amdgcn_mfma_f32_16x16x32_bf16(kf1, qf[es], st1, 0, 0, 0);
        }

        // causal mask: only the global diagonal tile
        if (ts + t == qt) {
#pragma unroll
            for (int r = 0; r < 4; r++) {
                if (kb + 4 * hi + r > qrow)      st0[r] = -1.0e4f;
                if (kb + 16 + 4 * hi + r > qrow) st1[r] = -1.0e4f;
            }
        }

        float tm = fmaxf(fmaxf(fmaxf(st0[0], st0[1]), fmaxf(st0[2], st0[3])),
                         fmaxf(fmaxf(st1[0], st1[1]), fmaxf(st1[2], st1[3])));
        tm = fmaxf(tm, __shfl_xor(tm, 16));
        tm = fmaxf(tm, __shfl_xor(tm, 32));
        if (__any(tm > m)) {
            float mn = fmaxf(m, tm);
            float sc = __expf(m - mn);
            m = mn; l *= sc;
            float scr[4];
#pragma unroll
            for (int r = 0; r < 4; r++) scr[r] = __shfl(sc, hi * 20 + r);
#pragma unroll
            for (int et = 0; et < 16; et++)
#pragma unroll
                for (int r = 0; r < 4; r++) o[et][r] *= scr[r];
        }
        float p0[4], p1[4];
#pragma unroll
        for (int r = 0; r < 4; r++) {
            p0[r] = __expf(st0[r] - m);
            p1[r] = __expf(st1[r] - m);
        }
        float rs = (p0[0] + p0[1]) + (p0[2] + p0[3]) + (p1[0] + p1[1]) + (p1[2] + p1[3]);
        rs += __shfl_xor(rs, 16);
        rs += __shfl_xor(rs, 32);
        l += rs;

        u32 pk00 = pack2bf(p0[0], p0[1]), pk01 = pack2bf(p0[2], p0[3]);
        u32 pk10 = pack2bf(p1[0], p1[1]), pk11 = pack2bf(p1[2], p1[3]);
        int sA = (lane & 15) | ((lane & 16) << 1);
        int sB = sA + 16;
        u32 b00 = (u32)__shfl((int)pk00, sA), b01 = (u32)__shfl((int)pk01, sA);
        u32 b02 = (u32)__shfl((int)pk00, sB), b03 = (u32)__shfl((int)pk01, sB);
        u32 b10 = (u32)__shfl((int)pk10, sA), b11 = (u32)__shfl((int)pk11, sA);
        u32 b12 = (u32)__shfl((int)pk10, sB), b13 = (u32)__shfl((int)pk11, sB);
        bool c1 = (hi & 2) != 0;
        union { uint4 u; s16x8 v; } pu;
        pu.u.x = c1 ? b10 : b00;
        pu.u.y = c1 ? b11 : b01;
        pu.u.z = c1 ? b12 : b02;
        pu.u.w = c1 ? b13 : b03;
        s16x8 pf = pu.v;

        // drain K(t+1)+V(t); keep K(t+2) in flight
        if (t + 2 < n) asm volatile("s_waitcnt vmcnt(8)" ::: "memory");
        else           asm volatile("s_waitcnt vmcnt(0)" ::: "memory");
        __builtin_amdgcn_sched_barrier(0);

#pragma unroll
        for (int et = 0; et < 16; et++) {
            union { uint4 u; s16x8 v; } vu; vu.u = vf[et];
            o[et] = __builtin_amdgcn_mfma_f32_16x16x32_bf16(pf, vu.v, o[et], 0, 0, 0);
        }

        __syncthreads();                       // K(t+1) visible to both waves
        char* tmp = kcur; kcur = knx1; knx1 = knx2; knx2 = tmp;
    }
    #undef KSTAGE

    // write partials: unnormalized O (bf16) + per-row m,l (fp32)
    if (hi == 0) {
        Pm[cid * 32 + wid * 16 + q] = m;
        Pl[cid * 32 + wid * 16 + q] = l;
    }
    u16* Pp = Ppart + (size_t)cid * 8192;
#pragma unroll
    for (int et = 0; et < 16; et++)
#pragma unroll
        for (int r = 0; r < 4; r++)
            Pp[(wid * 16 + 4 * hi + r) * 256 + q + 16 * et] = f2bf(o[et][r]);
}

// ---------------- Kernel B2: combine partials -> d_out ----------------
// 512 blocks (8b x 64qt) x 256 thr. Exact online-softmax merge of 1-2 chunks.
__global__ __launch_bounds__(256) void attn_combine(
    const u16* __restrict__ Ppart, const float* __restrict__ Pm,
    const float* __restrict__ Pl, float* __restrict__ outp)
{
    const int bid = blockIdx.x;
    const int bb  = bid & 7;
    const int qt  = bid >> 3;
    const int tid = threadIdx.x;
    const int r   = tid >> 3;            // row 0..31
    const int cg  = tid & 7;             // col group (32 cols)

    const int cidA = bb * 96 + qt;
    const float mA = Pm[cidA * 32 + r], lA = Pl[cidA * 32 + r];
    const u16* pA = Ppart + (size_t)cidA * 8192 + r * 256 + cg * 32;

    float w[64];
    float wa, wb, inv;
    const u16* pB = nullptr;
    if (qt >= 32) {
        const int cidB = bb * 96 + 64 + (qt - 32);
        float mB = Pm[cidB * 32 + r], lB = Pl[cidB * 32 + r];
        pB = Ppart + (size_t)cidB * 8192 + r * 256 + cg * 32;
        float M = fmaxf(mA, mB);
        wa = __expf(mA - M); wb = __expf(mB - M);
        inv = 1.0f / (lA * wa + lB * wb);
        wa *= inv; wb *= inv;
    } else {
        wa = 1.0f / lA; wb = 0.f;
    }

    float* dst = outp + ((size_t)bb * TWIN + qt * 32 + r) * NEMB + cg * 32;
#pragma unroll
    for (int v4 = 0; v4 < 4; v4++) {
        uint4 a = *(const uint4*)(pA + v4 * 8);
        u32 au[4] = {a.x, a.y, a.z, a.w};
        float ov[8];
#pragma unroll
        for (int i = 0; i < 4; i++) {
            ov[2 * i]     = bf2f((u16)(au[i] & 0xffffu)) * wa;
            ov[2 * i + 1] = bf2f((u16)(au[i] >> 16)) * wa;
        }
        if (pB) {
            uint4 b = *(const uint4*)(pB + v4 * 8);
            u32 bu[4] = {b.x, b.y, b.z, b.w};
#pragma unroll
            for (int i = 0; i < 4; i++) {
                ov[2 * i]     += bf2f((u16)(bu[i] & 0xffffu)) * wb;
                ov[2 * i + 1] += bf2f((u16)(bu[i] >> 16)) * wb;
            }
        }
#pragma unroll
        for (int i = 0; i < 8; i++) dst[v4 * 8 + i] = ov[i];
    }
    (void)w;
}

// ---------------- Kernel B-fallback: r11 barrier-free attention ----------------
__global__ __launch_bounds__(128) void attn_kernel(
    const u16* __restrict__ Qg, const u16* __restrict__ Kg,
    const u16* __restrict__ Vt, float* __restrict__ outp)
{
    __shared__ u16 k_lds[2][2][32 * 256];

    const int tid = threadIdx.x;
    const int bid = blockIdx.x;
    const int bb  = bid & 7;
    const int idx = bid >> 3;
    const int qtile = (idx < 32) ? (63 - idx) : (idx - 32);
    const int q0 = qtile * 32;
    const int nt = qtile + 1;

    const u16* Qb = Qg + (size_t)bb * TWIN * NEMB;
    const u16* Kb = Kg + (size_t)bb * TWIN * NEMB;
    const u16* Vb = Vt + (size_t)bb * NEMB * TWIN;
    float* Ob = outp + (size_t)bb * TWIN * NEMB;

    const int wid = tid >> 6, lane = tid & 63;
    const int q   = lane & 15, hi = lane >> 4;
    const int qrow = q0 + wid * 16 + q;

    s16x8 qf[8];
#pragma unroll
    for (int es = 0; es < 8; es++)
        qf[es] = *(const s16x8*)(Qb + (size_t)qrow * NEMB + es * 32 + hi * 8);

    char* kb0 = (char*)&k_lds[wid][0][0];
    char* kb1 = (char*)&k_lds[wid][1][0];

    #define KSTAGE2(dst_, kb_)                                                        \
    {                                                                                 \
        const int kbq_ = (kb_);                                                       \
        _Pragma("unroll")                                                             \
        for (int gc = 0; gc < 16; gc++) {                                             \
            int s = gc * 64 + lane;                                                   \
            int row = s >> 5, col16 = s & 31;                                         \
            const char* src = (const char*)(Kb + (size_t)(kbq_ + row) * NEMB)         \
                              + ((col16 * 16) ^ ((row & 7) << 4));                    \
            gload_lds16(src, (dst_) + gc * 1024);                                     \
        }                                                                             \
    }

    KSTAGE2(kb0, 0)

    f32x4 o[16];
#pragma unroll
    for (int i = 0; i < 16; i++) o[i] = (f32x4){0.f, 0.f, 0.f, 0.f};
    float m = -1.0e4f, l = 0.f;

    for (int t = 0; t < nt; t++) {
        const int kb = t * 32;
        const char* kcur = (t & 1) ? kb1 : kb0;
        char*       knxt = (t & 1) ? kb0 : kb1;

        uint4 vf[16];
        {
            unsigned long long va =
                (unsigned long long)(Vb + (size_t)q * TWIN + kb + hi * 8);
#pragma unroll
            for (int et = 0; et < 16; et++) {
                asm volatile("global_load_dwordx4 %0, %1, off"
                             : "=&v"(vf[et]) : "v"(va) : "memory");
                va += (unsigned long long)16 * TWIN * 2;
            }
        }
        if (t + 1 < nt) KSTAGE2(knxt, kb + 32)

        if (t + 1 < nt) asm volatile("s_waitcnt vmcnt(32)" ::: "memory");
        else            asm volatile("s_waitcnt vmcnt(16)" ::: "memory");
        __builtin_amdgcn_sched_barrier(0);

        f32x4 st0 = (f32x4){0.f, 0.f, 0.f, 0.f};
        f32x4 st1 = (f32x4){0.f, 0.f, 0.f, 0.f};
#pragma unroll
        for (int es = 0; es < 8; es++) {
            s16x8 kf0 = *(const s16x8*)(kcur + q * 512 +
                                        ((es * 64 + hi * 16) ^ ((q & 7) << 4)));
            st0 = __builtin_amdgcn_mfma_f32_16x16x32_bf16(kf0, qf[es], st0, 0, 0, 0);
            int row1 = q + 16;
            s16x8 kf1 = *(const s16x8*)(kcur + row1 * 512 +
                                        ((es * 64 + hi * 16) ^ ((row1 & 7) << 4)));
            st1 = __builtin_amdgcn_mfma_f32_16x16x32_bf16(kf1, qf[es], st1, 0, 0, 0);
        }

        if (t == nt - 1) {
#pragma unroll
            for (int r = 0; r < 4; r++) {
                if (kb + 4 * hi + r > qrow)      st0[r] = -1.0e4f;
                if (kb + 16 + 4 * hi + r > qrow) st1[r] = -1.0e4f;
            }
        }

        float tm = fmaxf(fmaxf(fmaxf(st0[0], st0[1]), fmaxf(st0[2], st0[3])),
                         fmaxf(fmaxf(st1[0], st1[1]), fmaxf(st1[2], st1[3])));
        tm = fmaxf(tm, __shfl_xor(tm, 16));
        tm = fmaxf(tm, __shfl_xor(tm, 32));
        if (__any(tm > m)) {
            float mn = fmaxf(m, tm);
            float sc = __expf(m - mn);
            m = mn; l *= sc;
            float scr[4];
#pragma unroll
            for (int r = 0; r < 4; r++) scr[r] = __shfl(sc, hi * 20 + r);
#pragma unroll
            for (int et = 0; et < 16; et++)
#pragma unroll
                for (int r = 0; r < 4; r++) o[et][r] *= scr[r];
        }
        float p0[4], p1[4];
#pragma unroll
        for (int r = 0; r < 4; r++) {
            p0[r] = __expf(st0[r] - m);
            p1[r] = __expf(st1[r] - m);
        }
        float rs = (p0[0] + p0[1]) + (p0[2] + p0[3]) + (p1[0] + p1[1]) + (p1[2] + p1[3]);
        rs += __shfl_xor(rs, 16);
        rs += __shfl_xor(rs, 32);
        l += rs;

        u32 pk00 = pack2bf(p0[0], p0[1]), pk01 = pack2bf(p0[2], p0[3]);
        u32 pk10 = pack2bf(p1[0], p1[1]), pk11 = pack2bf(p1[2], p1[3]);
        int sA = (lane & 15) | ((lane & 16) << 1);
        int sB = sA + 16;
        u32 b00 = (u32)__shfl((int)pk00, sA), b01 = (u32)__shfl((int)pk01, sA);
        u32 b02 = (u32)__shfl((int)pk00, sB), b03 = (u32)__shfl((int)pk01, sB);
        u32 b10 = (u32)__shfl((int)pk10, sA), b11 = (u32)__shfl((int)pk11, sA);
        u32 b12 = (u32)__shfl((int)pk10, sB), b13 = (u32)__shfl((int)pk11, sB);
        bool c1 = (hi & 2) != 0;
        union { uint4 u; s16x8 v; } pu;
        pu.u.x = c1 ? b10 : b00;
        pu.u.y = c1 ? b11 : b01;
        pu.u.z = c1 ? b12 : b02;
        pu.u.w = c1 ? b13 : b03;
        s16x8 pf = pu.v;

        if (t + 1 < nt) asm volatile("s_waitcnt vmcnt(16)" ::: "memory");
        else            asm volatile("s_waitcnt vmcnt(0)"  ::: "memory");
        __builtin_amdgcn_sched_barrier(0);

#pragma unroll
        for (int et = 0; et < 16; et++) {
            union { uint4 u; s16x8 v; } vu; vu.u = vf[et];
            o[et] = __builtin_amdgcn_mfma_f32_16x16x32_bf16(pf, vu.v, o[et], 0, 0, 0);
        }
    }
    #undef KSTAGE2

    float rinv = 1.0f / l;
    float invr[4];
#pragma unroll
    for (int r = 0; r < 4; r++) invr[r] = __shfl(rinv, hi * 20 + r);
#pragma unroll
    for (int et = 0; et < 16; et++) {
#pragma unroll
        for (int r = 0; r < 4; r++)
            Ob[(size_t)(q0 + wid * 16 + 4 * hi + r) * NEMB + q + 16 * et]
                = o[et][r] * invr[r];
    }
}

// ---------------- ws-too-small diagnostic ----------------
__global__ __launch_bounds__(256) void ws_diag(float* outp, int n, float val) {
    int i = blockIdx.x * 256 + threadIdx.x;
    if (i < n) outp[i] = (i == 0) ? val : 0.0f;
}

extern "C" void kernel_launch(void* const* d_in, const int* in_sizes, int n_in,
                              void* d_out, int out_size, void* d_ws, size_t ws_size,
                              hipStream_t stream)
{
    const void*  x   = d_in[0];
    const float* tok = (const float*)d_in[1];
    const float* pos = (const float*)d_in[2];
    const float* Wq  = (const float*)d_in[3];
    const float* bq  = (const float*)d_in[4];
    const float* Wk  = (const float*)d_in[5];
    const float* bk  = (const float*)d_in[6];
    const float* Wv  = (const float*)d_in[7];
    const float* bv  = (const float*)d_in[8];

    const size_t kvElems  = (size_t)NB * TWIN * NEMB;        // 4M u16 = 8MB
    const size_t wbElems  = 3 * 65536;
    const size_t nChunks  = 96 * NB;                          // 768
    const size_t pmBytes  = nChunks * 32 * sizeof(float);     // 96KB
    const size_t ppBytes  = nChunks * 8192 * sizeof(u16);     // 12.6MB

    const size_t needSplit = 2 * kvElems * 2 + wbElems * 2 + NTOK * 4
                           + 2 * pmBytes + ppBytes + 256;
    const size_t needOld   = 3 * kvElems * 2 + wbElems * 2 + NTOK * 4 + 64;

    if (ws_size >= needSplit) {
        // layout: K | Vt | Wb | tokidx | Pm | Pl | Ppart ; Q lives in d_out (bf16)
        u16* Kg = (u16*)d_ws;
        u16* Vt = Kg + kvElems;
        u16* Wb = Vt + kvElems;
        int* tokidx = (int*)(Wb + wbElems);
        float* Pm = (float*)((char*)tokidx + NTOK * 4);
        float* Pl = (float*)((char*)Pm + pmBytes);
        u16* Ppart = (u16*)((char*)Pl + pmBytes);
        u16* Qg = (u16*)d_out;

        hipLaunchKernelGGL(wconv_kernel, dim3(96), dim3(256), 0, stream, Wq, Wk, Wv, Wb);
        hipLaunchKernelGGL(tok_prep, dim3(64), dim3(256), 0, stream, x, tokidx);
        hipLaunchKernelGGL(qkv_kernel, dim3(1536), dim3(128), 0, stream,
                           tokidx, tok, pos, Wb, bq, bk, bv, Qg, Kg, Vt);
        hipLaunchKernelGGL(attn_partial, dim3(768), dim3(128), 0, stream,
                           Qg, Kg, Vt, Ppart, Pm, Pl);
        hipLaunchKernelGGL(attn_combine, dim3(512), dim3(256), 0, stream,
                           Ppart, Pm, Pl, (float*)d_out);
    } else if (ws_size >= needOld) {
        // fallback: r11 structure, Q in ws
        u16* Qg = (u16*)d_ws;
        u16* Kg = Qg + kvElems;
        u16* Vt = Kg + kvElems;
        u16* Wb = Vt + kvElems;
        int* tokidx = (int*)(Wb + wbElems);

        hipLaunchKernelGGL(wconv_kernel, dim3(96), dim3(256), 0, stream, Wq, Wk, Wv, Wb);
        hipLaunchKernelGGL(tok_prep, dim3(64), dim3(256), 0, stream, x, tokidx);
        hipLaunchKernelGGL(qkv_kernel, dim3(1536), dim3(128), 0, stream,
                           tokidx, tok, pos, Wb, bq, bk, bv, Qg, Kg, Vt);
        hipLaunchKernelGGL(attn_kernel, dim3(512), dim3(128), 0, stream,
                           Qg, Kg, Vt, (float*)d_out);
    } else {
        float val = 1000.0f + (float)(ws_size >> 20);
        hipLaunchKernelGGL(ws_diag, dim3((out_size + 255) / 256), dim3(256), 0, stream,
                           (float*)d_out, out_size, val);
    }
}